// Round 8
// baseline (220.134 us; speedup 1.0000x reference)
//
#include <hip/hip_runtime.h>

#define TPB 256
#define EPT 8
#define CHUNK (TPB * EPT)   // 2048 elements per block
#define NSLICE 64           // histogram slices to spread global atomics

typedef unsigned long long ull;

__device__ __forceinline__ ull shfl_down_u64(ull x, int off) {
    unsigned lo = (unsigned)x, hi = (unsigned)(x >> 32);
    lo = __shfl_down(lo, off, 64);
    hi = __shfl_down(hi, off, 64);
    return ((ull)hi << 32) | lo;
}
__device__ __forceinline__ int aload32(int* p) {
    return __hip_atomic_load(p, __ATOMIC_RELAXED, __HIP_MEMORY_SCOPE_AGENT);
}
__device__ __forceinline__ ull aload64(ull* p) {
    return __hip_atomic_load(p, __ATOMIC_RELAXED, __HIP_MEMORY_SCOPE_AGENT);
}
__device__ __forceinline__ void astore64(ull* p, ull v) {
    __hip_atomic_store(p, v, __ATOMIC_RELAXED, __HIP_MEMORY_SCOPE_AGENT);
}

// ---------------------------------------------------------------------------
// Pass 1: per-element pre-shift compute + histograms + block sums.
// Cross-block data transfer is atomics-only (L3-coherent, no fences).
// Counter-winner block performs the former pass2: pos_offset scan, shift,
// histogram output (wtq7/bits6 derived from q_hist64).
// ---------------------------------------------------------------------------
__global__ __launch_bounds__(TPB, 4) void k_pass1(
    const float* __restrict__ blp, const int* __restrict__ st,
    const int* __restrict__ q, const int* __restrict__ fam,
    const int* __restrict__ mic, const int* __restrict__ vm,
    float* __restrict__ out_structural,
    int* __restrict__ bsum_v, ull* __restrict__ bsum_c,
    int* __restrict__ ghist, int* __restrict__ ctrl,
    int* __restrict__ pos_offset, float* __restrict__ shiftp,
    int* __restrict__ totalv_p, float* __restrict__ out_hist, int n, int nb)
{
    __shared__ int lh2[512];     // per-wave q64 | per-wave micro64 (later: qh[64])
    __shared__ int slhs[11];     // 0-3 fam, 4-10 shell
    __shared__ int swv[4];
    __shared__ float swc[4];
    __shared__ int sLast;
    __shared__ int escan[TPB];
    __shared__ double edbl[TPB];
    for (int t = threadIdx.x; t < 512; t += TPB) lh2[t] = 0;
    if (threadIdx.x < 11) slhs[threadIdx.x] = 0;
    __syncthreads();

    const int tid = threadIdx.x, lane = tid & 63, wave = tid >> 6;
    const long i0 = (long)blockIdx.x * CHUNK + (long)tid * EPT;
    const bool fast = ((long)(blockIdx.x + 1) * CHUNK <= n);

    int stv[9], qv[9], fv[9], micv[8], vmv[8];
    float bpv[8];
    if (fast) {
        const int4 sa = *(const int4*)(st + i0),  sb = *(const int4*)(st + i0 + 4);
        const int4 qa = *(const int4*)(q + i0),   qb = *(const int4*)(q + i0 + 4);
        const int4 fa = *(const int4*)(fam + i0), fb = *(const int4*)(fam + i0 + 4);
        const int4 ma = *(const int4*)(mic + i0), mb = *(const int4*)(mic + i0 + 4);
        const int4 va = *(const int4*)(vm + i0),  vb = *(const int4*)(vm + i0 + 4);
        const float4 ba = *(const float4*)(blp + i0), bb = *(const float4*)(blp + i0 + 4);
        int nst = __shfl_down(sa.x, 1, 64);
        int nq  = __shfl_down(qa.x, 1, 64);
        int nf  = __shfl_down(fa.x, 1, 64);
        if (lane == 63) {
            const long j = i0 + 8;
            nst = (j < n) ? st[j]  : 0;
            nq  = (j < n) ? q[j]   : 0;
            nf  = (j < n) ? fam[j] : 0;
        }
        stv[0]=sa.x; stv[1]=sa.y; stv[2]=sa.z; stv[3]=sa.w; stv[4]=sb.x; stv[5]=sb.y; stv[6]=sb.z; stv[7]=sb.w; stv[8]=nst;
        qv[0]=qa.x;  qv[1]=qa.y;  qv[2]=qa.z;  qv[3]=qa.w;  qv[4]=qb.x;  qv[5]=qb.y;  qv[6]=qb.z;  qv[7]=qb.w;  qv[8]=nq;
        fv[0]=fa.x;  fv[1]=fa.y;  fv[2]=fa.z;  fv[3]=fa.w;  fv[4]=fb.x;  fv[5]=fb.y;  fv[6]=fb.z;  fv[7]=fb.w;  fv[8]=nf;
        micv[0]=ma.x; micv[1]=ma.y; micv[2]=ma.z; micv[3]=ma.w; micv[4]=mb.x; micv[5]=mb.y; micv[6]=mb.z; micv[7]=mb.w;
        vmv[0]=va.x; vmv[1]=va.y; vmv[2]=va.z; vmv[3]=va.w; vmv[4]=vb.x; vmv[5]=vb.y; vmv[6]=vb.z; vmv[7]=vb.w;
        bpv[0]=ba.x; bpv[1]=ba.y; bpv[2]=ba.z; bpv[3]=ba.w; bpv[4]=bb.x; bpv[5]=bb.y; bpv[6]=bb.z; bpv[7]=bb.w;
    } else {
        #pragma unroll
        for (int e = 0; e < 8; ++e) {
            long ii = i0 + e;
            bool r = ii < n;
            stv[e] = r ? st[ii] : 0;  qv[e] = r ? q[ii] : 0;  fv[e] = r ? fam[ii] : 0;
            micv[e] = r ? mic[ii] : 0; vmv[e] = r ? vm[ii] : 0; bpv[e] = r ? blp[ii] : 0.f;
        }
        stv[8] = (i0 + 8 < n) ? st[i0 + 8] : 0;
        qv[8]  = (i0 + 8 < n) ? q[i0 + 8] : 0;
        fv[8]  = (i0 + 8 < n) ? fam[i0 + 8] : 0;
    }

    int sv = 0;
    float scf = 0.0f;
    ull accF = 0, accS0 = 0, accS1 = 0;
    float structural[8];
    #pragma unroll
    for (int e = 0; e < 8; ++e) {
        int sti = stv[e], qi = qv[e], fi = fv[e], mi = micv[e];
        int v = (vmv[e] != 0);
        int om  = sti & 0xFFF;      int c6  = ((om  >> 6) ^ om ) & 63;
        int omn = stv[e+1] & 0xFFF; int c6n = ((omn >> 6) ^ omn) & 63;
        float d_chi = (float)__popc(c6 ^ c6n) * (1.0f / 6.0f);
        float d_q   = (float)__popc((qi & 63) ^ (qv[e+1] & 63)) * (1.0f / 6.0f);
        int fx = (fi & 3) ^ (fv[e+1] & 3);
        float d_fam = (float)((fx & 1) + ((fx >> 1) & 1)) * 0.5f;
        float score = 0.5f * d_chi + 0.35f * d_q + 0.15f * d_fam;
        score = fminf(fmaxf(score, 1e-6f), 1.0f);
        structural[e] = v ? score : 0.0f;
        float cosine = expf(fminf(bpv[e], 0.0f));
        float combined = 0.5f * (cosine + structural[e]);
        if (v) {
            sv += 1;
            scf += combined;
            atomicAdd(&lh2[(wave << 6) + (qi & 63)], 1);
            atomicAdd(&lh2[256 + (wave << 6) + (mi & 63)], 1);
            accF += 1ULL << ((fi & 3) * 16);
            int sh = __popc(c6);
            ull ts = 1ULL << ((sh & 3) * 16);
            if (sh < 4) accS0 += ts; else accS1 += ts;
        }
    }

    if (fast) {
        float4 o;
        o.x=structural[0]; o.y=structural[1]; o.z=structural[2]; o.w=structural[3];
        *(float4*)(out_structural + i0) = o;
        o.x=structural[4]; o.y=structural[5]; o.z=structural[6]; o.w=structural[7];
        *(float4*)(out_structural + i0 + 4) = o;
    } else {
        #pragma unroll
        for (int e = 0; e < 8; ++e)
            if (i0 + e < n) out_structural[i0 + e] = structural[e];
    }

    #pragma unroll
    for (int off = 32; off > 0; off >>= 1) {
        sv  += __shfl_down(sv, off, 64);
        scf += __shfl_down(scf, off, 64);
        accF  += shfl_down_u64(accF, off);
        accS0 += shfl_down_u64(accS0, off);
        accS1 += shfl_down_u64(accS1, off);
    }
    if (lane == 0) {
        swv[wave] = sv; swc[wave] = scf;
        #pragma unroll
        for (int b2 = 0; b2 < 4; ++b2) atomicAdd(&slhs[b2],     (int)((accF  >> (16*b2)) & 0xFFFF));
        #pragma unroll
        for (int b2 = 0; b2 < 4; ++b2) atomicAdd(&slhs[4 + b2], (int)((accS0 >> (16*b2)) & 0xFFFF));
        #pragma unroll
        for (int b2 = 0; b2 < 3; ++b2) atomicAdd(&slhs[8 + b2], (int)((accS1 >> (16*b2)) & 0xFFFF));
    }
    __syncthreads();
    if (tid == 0) {
        int bv = swv[0] + swv[1] + swv[2] + swv[3];
        double bc = (double)swc[0] + (double)swc[1] + (double)swc[2] + (double)swc[3];
        atomicExch(&bsum_v[blockIdx.x], bv);                      // L3-visible
        atomicExch(&bsum_c[blockIdx.x], __double_as_longlong(bc));
    }
    // global merge (bins 0..138; wtq/bits derived later from q_hist64)
    int* gh = ghist + (blockIdx.x & (NSLICE - 1)) * 152;
    for (int t2 = tid; t2 < 139; t2 += TPB) {
        int val;
        if (t2 < 64)        val = lh2[t2] + lh2[64 + t2] + lh2[128 + t2] + lh2[192 + t2];
        else if (t2 < 68)   val = slhs[t2 - 64];
        else if (t2 < 132) { int b2 = t2 - 68; val = lh2[128 + 128 + b2] + lh2[256 + 64 + b2] + lh2[384 + b2] + lh2[448 + b2]; }
        else                val = slhs[4 + (t2 - 132)];
        if (val) atomicAdd(&gh[t2], val);
    }
    // NOTE: micro rows are lh2[256..511]; rewrite index above cleanly:
    // (kept equivalent: 128+128+b2 = 256+b2, 256+64+b2 = 320+b2)

    __syncthreads();   // drains all this block's atomics (vmcnt(0) before barrier)
    if (tid == 0) sLast = (atomicAdd(&ctrl[0], 1) == nb - 1);
    __syncthreads();
    if (!sLast) return;

    // ---- winner block: former pass2 ----
    const int G = (nb + TPB - 1) / TPB;          // chunks per thread (8 for nb=2048)
    int myv[16];
    int msum = 0;
    double myd = 0.0;
    for (int g = 0; g < G; ++g) {
        int j = tid * G + g;
        int v = 0;
        if (j < nb) {
            v = aload32(&bsum_v[j]);
            myd += __longlong_as_double(aload64(&bsum_c[j]));
        }
        myv[g] = v;
        msum += v;
    }
    escan[tid] = msum;
    edbl[tid] = myd;
    __syncthreads();
    for (int off = 1; off < TPB; off <<= 1) {
        int add = (tid >= off) ? escan[tid - off] : 0;
        __syncthreads();
        escan[tid] += add;
        __syncthreads();
    }
    int run = escan[tid] - msum;
    for (int g = 0; g < G; ++g) {
        int j = tid * G + g;
        if (j < nb) { pos_offset[j] = run; run += myv[g]; }
    }
    for (int off = TPB / 2; off > 0; off >>= 1) {
        if (tid < off) edbl[tid] += edbl[tid + off];
        __syncthreads();
    }
    if (tid == 0) {
        int total_v = escan[TPB - 1];
        *totalv_p = total_v;
        double vc = (double)(total_v > 1 ? total_v : 1);
        float cur = (float)(edbl[0] / vc);
        cur = fminf(fmaxf(cur, 1e-4f), 0.9999f);
        float p = fminf(fmaxf(cur, 1e-6f), 0.999999f);
        float lc = logf(p) - log1pf(-p);
        float tgt = (float)(1.0 / 6.0);
        float lt = logf(tgt) - log1pf(-tgt);
        *shiftp = lt - lc;
    }
    // histogram output: direct bins + derived wtq7/bits6
    for (int t2 = tid; t2 < 139; t2 += TPB) {
        int acc = 0;
        #pragma unroll 8
        for (int sl = 0; sl < NSLICE; ++sl) acc += aload32(&ghist[sl * 152 + t2]);
        out_hist[t2] = (float)acc;
        if (t2 < 64) lh2[t2] = acc;              // stash q_hist64
    }
    __syncthreads();
    if (tid < 7) {
        int s = 0;
        for (int b = 0; b < 64; ++b) if (__popc(b) == tid) s += lh2[b];
        out_hist[139 + tid] = (float)s;
    }
    if (tid < 6) {
        int s = 0;
        for (int b = 0; b < 64; ++b) s += lh2[b] * ((b >> tid) & 1);
        out_hist[146 + tid] = (float)s;
    }
}

// ---------------------------------------------------------------------------
// Pass 3: recompute combined from structural (>0 iff valid) + blp; apply
// shift -> logp/bmask; in-block run lengths with exact cross-chunk carry via
// nearest-boundary-predecessor polling (positions are globally monotone, so
// carry = lastPos of the nearest predecessor chunk with a boundary).
// Counter-winner writes trailing/patch_count.
// ---------------------------------------------------------------------------
__global__ __launch_bounds__(TPB, 8) void k_pass3(
    const float* __restrict__ strc, const float* __restrict__ blp,
    const float* __restrict__ shiftp, const int* __restrict__ pos_offset,
    float* __restrict__ out_logp, float* __restrict__ out_bmask,
    float* __restrict__ out_len, ull* __restrict__ desc,
    int* __restrict__ ctrl, const int* __restrict__ totalv_p,
    float* __restrict__ out_trailing, float* __restrict__ out_patch, int n, int nb)
{
    __shared__ int swt[4], swm[4], scnt[4];
    __shared__ int scarry, sLast;
    const int tid = threadIdx.x, lane = tid & 63, wave = tid >> 6;
    const int b = blockIdx.x;
    const long i0 = (long)b * CHUNK + (long)tid * EPT;
    const bool fast = ((long)(b + 1) * CHUNK <= n);
    const float shift = *shiftp;

    float sv8[8], bp8[8];
    if (fast) {
        const float4 s0 = *(const float4*)(strc + i0), s1 = *(const float4*)(strc + i0 + 4);
        const float4 p0 = *(const float4*)(blp + i0),  p1 = *(const float4*)(blp + i0 + 4);
        sv8[0]=s0.x; sv8[1]=s0.y; sv8[2]=s0.z; sv8[3]=s0.w; sv8[4]=s1.x; sv8[5]=s1.y; sv8[6]=s1.z; sv8[7]=s1.w;
        bp8[0]=p0.x; bp8[1]=p0.y; bp8[2]=p0.z; bp8[3]=p0.w; bp8[4]=p1.x; bp8[5]=p1.y; bp8[6]=p1.z; bp8[7]=p1.w;
    } else {
        #pragma unroll
        for (int e = 0; e < 8; ++e) {
            long ii = i0 + e;
            bool r = ii < n;
            sv8[e] = r ? strc[ii] : 0.0f;
            bp8[e] = r ? blp[ii] : 0.0f;
        }
    }

    unsigned mv = 0, mb = 0;
    float lp[8], bmf[8], lenv[8];
    #pragma unroll
    for (int e = 0; e < 8; ++e) {
        float s = sv8[e];
        int v = (s > 0.0f);
        float cosine = expf(fminf(bp8[e], 0.0f));
        float comb = 0.5f * (cosine + s);
        float p = fminf(fmaxf(comb, 1e-6f), 0.999999f);
        float z = logf(p) - log1pf(-p) + shift;
        float sgm = 1.0f / (1.0f + expf(-z));
        sgm = fminf(fmaxf(sgm, 1e-6f), 0.999999f);
        float clp = logf(sgm);
        lp[e] = clp;
        int bm = (clp >= -0.69314718f) ? 1 : 0;
        bmf[e] = (float)bm;
        mv |= (unsigned)v << e;
        if (bm & v) mb |= 1u << e;
        lenv[e] = 0.0f;
    }
    if (fast) {
        float4 o;
        o.x=lp[0]; o.y=lp[1]; o.z=lp[2]; o.w=lp[3];     *(float4*)(out_logp + i0) = o;
        o.x=lp[4]; o.y=lp[5]; o.z=lp[6]; o.w=lp[7];     *(float4*)(out_logp + i0 + 4) = o;
        o.x=bmf[0]; o.y=bmf[1]; o.z=bmf[2]; o.w=bmf[3]; *(float4*)(out_bmask + i0) = o;
        o.x=bmf[4]; o.y=bmf[5]; o.z=bmf[6]; o.w=bmf[7]; *(float4*)(out_bmask + i0 + 4) = o;
    } else {
        #pragma unroll
        for (int e = 0; e < 8; ++e)
            if (i0 + e < n) { out_logp[i0 + e] = lp[e]; out_bmask[i0 + e] = bmf[e]; }
    }

    // block-wide exclusive valid-count prefix
    int tvc = __popc(mv);
    int x = tvc;
    #pragma unroll
    for (int off = 1; off < 64; off <<= 1) {
        int y = __shfl_up(x, off, 64);
        if (lane >= off) x += y;
    }
    if (lane == 63) swt[wave] = x;
    __syncthreads();
    int wb = pos_offset[b];
    for (int w2 = 0; w2 < wave; ++w2) wb += swt[w2];
    const int vbase = wb + (x - tvc);

    // in-wave last-boundary max-scan + count reduction
    int last = -1;
    if (mb) {
        int hb = 31 - __clz(mb);
        last = vbase + __popc(mv & ((2u << hb) - 1));
    }
    int m = last;
    #pragma unroll
    for (int off = 1; off < 64; off <<= 1) {
        int y = __shfl_up(m, off, 64);
        if (lane >= off && y > m) m = y;
    }
    int exm = __shfl_up(m, 1, 64);
    if (lane == 0) exm = -1;
    if (lane == 63) swm[wave] = m;
    int cnt = __popc(mb);
    #pragma unroll
    for (int off = 32; off > 0; off >>= 1) cnt += __shfl_down(cnt, off, 64);
    if (lane == 0) scnt[wave] = cnt;
    __syncthreads();

    // tid0: publish own (hasB,lastPos); poll nearest boundary-predecessor
    if (tid == 0) {
        int L = swm[0];
        if (swm[1] > L) L = swm[1];
        if (swm[2] > L) L = swm[2];
        if (swm[3] > L) L = swm[3];
        int hasB = (L >= 0);
        astore64(&desc[b], (1ULL << 63) | ((ull)hasB << 62) | (unsigned)(hasB ? L : 0));
        int carry = 0;
        for (int j = b - 1; j >= 0; ) {
            ull v = aload64(&desc[j]);
            if (!(v >> 63)) { __builtin_amdgcn_s_sleep(1); continue; }
            if ((v >> 62) & 1) { carry = (int)(unsigned)(v & 0xFFFFFFFFu); break; }
            --j;
        }
        scarry = carry;
        int c = scnt[0] + scnt[1] + scnt[2] + scnt[3];
        atomicAdd(&ctrl[3], c);                              // global patch-boundary count
        if (b == nb - 1) {
            int incl = hasB ? L : carry;
            atomicExch(&ctrl[2], incl);                      // global max boundary pos
        }
    }
    __syncthreads();

    int prev = scarry;
    for (int w2 = 0; w2 < wave; ++w2) if (swm[w2] > prev) prev = swm[w2];
    if (exm > prev) prev = exm;
    int runv = 0;
    #pragma unroll
    for (int e = 0; e < 8; ++e) {
        runv += (mv >> e) & 1;
        if ((mb >> e) & 1) {
            int pos = vbase + runv;
            lenv[e] = (float)(pos - prev);
            prev = pos;
        }
    }
    if (fast) {
        float4 o;
        o.x=lenv[0]; o.y=lenv[1]; o.z=lenv[2]; o.w=lenv[3]; *(float4*)(out_len + i0) = o;
        o.x=lenv[4]; o.y=lenv[5]; o.z=lenv[6]; o.w=lenv[7]; *(float4*)(out_len + i0 + 4) = o;
    } else {
        #pragma unroll
        for (int e = 0; e < 8; ++e)
            if (i0 + e < n) out_len[i0 + e] = lenv[e];
    }

    __syncthreads();   // drains this block's atomics before the counter add
    if (tid == 0) sLast = (atomicAdd(&ctrl[1], 1) == nb - 1);
    __syncthreads();
    if (!sLast) return;
    if (tid == 0) {
        int gmax = aload32(&ctrl[2]);
        int gcnt = aload32(&ctrl[3]);
        int total_v = *totalv_p;
        int trailing = total_v - gmax;
        int patch = gcnt + (trailing > 0 ? 1 : 0);
        *out_trailing = (float)trailing;
        *out_patch = (float)patch;
    }
}

// ---------------------------------------------------------------------------
extern "C" void kernel_launch(void* const* d_in, const int* in_sizes, int n_in,
                              void* d_out, int out_size, void* d_ws, size_t ws_size,
                              hipStream_t stream)
{
    const float* blp = (const float*)d_in[0];
    const int* st   = (const int*)d_in[1];
    const int* q    = (const int*)d_in[2];
    const int* fam  = (const int*)d_in[3];
    const int* mic  = (const int*)d_in[4];
    const int* vm   = (const int*)d_in[5];
    const int n = in_sizes[0];
    const int nb = (n + CHUNK - 1) / CHUNK;          // 2048 for n=4M

    float* out = (float*)d_out;
    float* out_logp       = out;
    float* out_bmask      = out + (size_t)n;
    float* out_structural = out + 2 * (size_t)n;
    float* out_hist       = out + 3 * (size_t)n;     // 152 floats
    float* out_len        = out + 3 * (size_t)n + 152;
    float* out_trailing   = out + 4 * (size_t)n + 152;
    float* out_patch      = out + 4 * (size_t)n + 153;

    char* w = (char*)d_ws;
    // --- zeroed region (one memset) ---
    int*  ghist  = (int*)(w);                        // 64*152 ints = 38912 B
    ull*  desc   = (ull*)(w + 40960);                // nb ulls (<= 32 KB)
    int*  ctrl   = (int*)(w + 73728);                // [0] p1 counter, [1] p3 counter, [2] gmax, [3] gcnt
    // --- non-zeroed region (always written before read) ---
    int*  bsum_v = (int*)(w + 81920);                // nb ints
    ull*  bsum_c = (ull*)(w + 114688);               // nb ulls
    int*  pos_offset = (int*)(w + 147456);           // nb ints
    float* shiftp    = (float*)(w + 180224);
    int*   totalv_p  = (int*)(w + 180228);

    hipMemsetAsync(w, 0, 73728 + 64, stream);

    k_pass1<<<dim3(nb), dim3(TPB), 0, stream>>>(
        blp, st, q, fam, mic, vm, out_structural,
        bsum_v, bsum_c, ghist, ctrl,
        pos_offset, shiftp, totalv_p, out_hist, n, nb);

    k_pass3<<<dim3(nb), dim3(TPB), 0, stream>>>(
        out_structural, blp, shiftp, pos_offset, out_logp, out_bmask,
        out_len, desc, ctrl, totalv_p, out_trailing, out_patch, n, nb);
}

// Round 9
// 192.036 us; speedup vs baseline: 1.1463x; 1.1463x over previous
//
#include <hip/hip_runtime.h>

#define TPB 256
#define EPT 8
#define CHUNK (TPB * EPT)   // 2048 elements per block
#define P2T 1024            // single-block scan kernels
#define NSLICE 64           // histogram slices to spread global atomics

typedef unsigned long long ull;

__device__ __forceinline__ ull shfl_down_u64(ull x, int off) {
    unsigned lo = (unsigned)x, hi = (unsigned)(x >> 32);
    lo = __shfl_down(lo, off, 64);
    hi = __shfl_down(hi, off, 64);
    return ((ull)hi << 32) | lo;
}

// ---------------------------------------------------------------------------
// Pass 1: per-element pre-shift compute + histograms + block sums.
// q64/micro64 in 16 LDS sub-rows (4 per wave, lane&3) to cut same-address
// atomic serialization; wtq7/bits6 derived later from q_hist64 (pass2);
// global merge into 64 slices (R7 win).
// ---------------------------------------------------------------------------
__global__ __launch_bounds__(TPB, 4) void k_pass1(
    const float* __restrict__ blp, const int* __restrict__ st,
    const int* __restrict__ q, const int* __restrict__ fam,
    const int* __restrict__ mic, const int* __restrict__ vm,
    float* __restrict__ out_structural,
    int* __restrict__ blocksum_v, double* __restrict__ blocksum_c,
    int* __restrict__ ghist, int n)
{
    __shared__ int lh2[2048];    // [0..1023] q64 x 16 rows | [1024..2047] micro64 x 16 rows
    __shared__ int slhs[11];     // 0-3 fam, 4-10 shell
    __shared__ int swv[4];
    __shared__ float swc[4];

    const int tid = threadIdx.x, lane = tid & 63, wave = tid >> 6;
    const long i0 = (long)blockIdx.x * CHUNK + (long)tid * EPT;
    const bool fast = ((long)(blockIdx.x + 1) * CHUNK <= n);

    // ---- loads first: 6 dwordx4 in flight during LDS init + barrier ----
    int stv[9], qv[9], fv[9], micv[8], vmv[8];
    float bpv[8];
    if (fast) {
        const int4 sa = *(const int4*)(st + i0),  sb = *(const int4*)(st + i0 + 4);
        const int4 qa = *(const int4*)(q + i0),   qb = *(const int4*)(q + i0 + 4);
        const int4 fa = *(const int4*)(fam + i0), fb = *(const int4*)(fam + i0 + 4);
        const int4 ma = *(const int4*)(mic + i0), mb = *(const int4*)(mic + i0 + 4);
        const int4 va = *(const int4*)(vm + i0),  vb = *(const int4*)(vm + i0 + 4);
        const float4 ba = *(const float4*)(blp + i0), bb = *(const float4*)(blp + i0 + 4);
        int nst = __shfl_down(sa.x, 1, 64);
        int nq  = __shfl_down(qa.x, 1, 64);
        int nf  = __shfl_down(fa.x, 1, 64);
        if (lane == 63) {
            const long j = i0 + 8;
            nst = (j < n) ? st[j]  : 0;
            nq  = (j < n) ? q[j]   : 0;
            nf  = (j < n) ? fam[j] : 0;
        }
        stv[0]=sa.x; stv[1]=sa.y; stv[2]=sa.z; stv[3]=sa.w; stv[4]=sb.x; stv[5]=sb.y; stv[6]=sb.z; stv[7]=sb.w; stv[8]=nst;
        qv[0]=qa.x;  qv[1]=qa.y;  qv[2]=qa.z;  qv[3]=qa.w;  qv[4]=qb.x;  qv[5]=qb.y;  qv[6]=qb.z;  qv[7]=qb.w;  qv[8]=nq;
        fv[0]=fa.x;  fv[1]=fa.y;  fv[2]=fa.z;  fv[3]=fa.w;  fv[4]=fb.x;  fv[5]=fb.y;  fv[6]=fb.z;  fv[7]=fb.w;  fv[8]=nf;
        micv[0]=ma.x; micv[1]=ma.y; micv[2]=ma.z; micv[3]=ma.w; micv[4]=mb.x; micv[5]=mb.y; micv[6]=mb.z; micv[7]=mb.w;
        vmv[0]=va.x; vmv[1]=va.y; vmv[2]=va.z; vmv[3]=va.w; vmv[4]=vb.x; vmv[5]=vb.y; vmv[6]=vb.z; vmv[7]=vb.w;
        bpv[0]=ba.x; bpv[1]=ba.y; bpv[2]=ba.z; bpv[3]=ba.w; bpv[4]=bb.x; bpv[5]=bb.y; bpv[6]=bb.z; bpv[7]=bb.w;
    } else {
        #pragma unroll
        for (int e = 0; e < 8; ++e) {
            long ii = i0 + e;
            bool r = ii < n;
            stv[e] = r ? st[ii] : 0;  qv[e] = r ? q[ii] : 0;  fv[e] = r ? fam[ii] : 0;
            micv[e] = r ? mic[ii] : 0; vmv[e] = r ? vm[ii] : 0; bpv[e] = r ? blp[ii] : 0.f;
        }
        stv[8] = (i0 + 8 < n) ? st[i0 + 8] : 0;
        qv[8]  = (i0 + 8 < n) ? q[i0 + 8] : 0;
        fv[8]  = (i0 + 8 < n) ? fam[i0 + 8] : 0;
    }

    for (int t = tid; t < 2048; t += TPB) lh2[t] = 0;
    if (tid < 11) slhs[tid] = 0;
    __syncthreads();

    const int qrow = ((wave << 2) | (lane & 3)) << 6;        // 16 sub-rows
    int sv = 0;
    float scf = 0.0f;
    ull accF = 0, accS0 = 0, accS1 = 0;
    float structural[8];
    #pragma unroll
    for (int e = 0; e < 8; ++e) {
        int sti = stv[e], qi = qv[e], fi = fv[e], mi = micv[e];
        int v = (vmv[e] != 0);
        int om  = sti & 0xFFF;      int c6  = ((om  >> 6) ^ om ) & 63;
        int omn = stv[e+1] & 0xFFF; int c6n = ((omn >> 6) ^ omn) & 63;
        float d_chi = (float)__popc(c6 ^ c6n) * (1.0f / 6.0f);
        float d_q   = (float)__popc((qi & 63) ^ (qv[e+1] & 63)) * (1.0f / 6.0f);
        int fx = (fi & 3) ^ (fv[e+1] & 3);
        float d_fam = (float)((fx & 1) + ((fx >> 1) & 1)) * 0.5f;
        float score = 0.5f * d_chi + 0.35f * d_q + 0.15f * d_fam;
        score = fminf(fmaxf(score, 1e-6f), 1.0f);
        structural[e] = v ? score : 0.0f;
        float cosine = expf(fminf(bpv[e], 0.0f));
        float combined = 0.5f * (cosine + structural[e]);
        if (v) {
            sv += 1;
            scf += combined;
            atomicAdd(&lh2[qrow + (qi & 63)], 1);
            atomicAdd(&lh2[1024 + qrow + (mi & 63)], 1);
            accF += 1ULL << ((fi & 3) * 16);
            int sh = __popc(c6);
            ull ts = 1ULL << ((sh & 3) * 16);
            if (sh < 4) accS0 += ts; else accS1 += ts;
        }
    }

    if (fast) {
        float4 o;
        o.x=structural[0]; o.y=structural[1]; o.z=structural[2]; o.w=structural[3];
        *(float4*)(out_structural + i0) = o;
        o.x=structural[4]; o.y=structural[5]; o.z=structural[6]; o.w=structural[7];
        *(float4*)(out_structural + i0 + 4) = o;
    } else {
        #pragma unroll
        for (int e = 0; e < 8; ++e)
            if (i0 + e < n) out_structural[i0 + e] = structural[e];
    }

    #pragma unroll
    for (int off = 32; off > 0; off >>= 1) {
        sv  += __shfl_down(sv, off, 64);
        scf += __shfl_down(scf, off, 64);
        accF  += shfl_down_u64(accF, off);
        accS0 += shfl_down_u64(accS0, off);
        accS1 += shfl_down_u64(accS1, off);
    }
    if (lane == 0) {
        swv[wave] = sv; swc[wave] = scf;
        #pragma unroll
        for (int b2 = 0; b2 < 4; ++b2) atomicAdd(&slhs[b2],     (int)((accF  >> (16*b2)) & 0xFFFF));
        #pragma unroll
        for (int b2 = 0; b2 < 4; ++b2) atomicAdd(&slhs[4 + b2], (int)((accS0 >> (16*b2)) & 0xFFFF));
        #pragma unroll
        for (int b2 = 0; b2 < 3; ++b2) atomicAdd(&slhs[8 + b2], (int)((accS1 >> (16*b2)) & 0xFFFF));
    }
    __syncthreads();
    if (tid == 0) {
        blocksum_v[blockIdx.x] = swv[0] + swv[1] + swv[2] + swv[3];
        blocksum_c[blockIdx.x] = (double)swc[0] + (double)swc[1] + (double)swc[2] + (double)swc[3];
    }
    // merge bins 0..138 (139..151 derived in pass2 from q_hist64)
    int* gh = ghist + (blockIdx.x & (NSLICE - 1)) * 152;
    for (int t2 = tid; t2 < 139; t2 += TPB) {
        int val;
        if (t2 < 64) {
            val = 0;
            #pragma unroll
            for (int r = 0; r < 16; ++r) val += lh2[(r << 6) + t2];
        } else if (t2 < 68) {
            val = slhs[t2 - 64];
        } else if (t2 < 132) {
            int b2 = t2 - 68;
            val = 0;
            #pragma unroll
            for (int r = 0; r < 16; ++r) val += lh2[1024 + (r << 6) + b2];
        } else {
            val = slhs[4 + (t2 - 132)];
        }
        if (val) atomicAdd(&gh[t2], val);
    }
}

// ---------------------------------------------------------------------------
// Pass 2: scan per-chunk valid counts (2/thread) -> pos_offset, totalv, shift;
// sum histogram slices; derive wtq7/bits6 from q_hist64.
// ---------------------------------------------------------------------------
__global__ __launch_bounds__(P2T) void k_pass2(
    const int* __restrict__ bsv, const double* __restrict__ bsc, int nb,
    int* __restrict__ pos_offset, float* __restrict__ shiftp,
    int* __restrict__ totalv_p, const int* __restrict__ ghist,
    float* __restrict__ out_hist)
{
    __shared__ int s[P2T];
    __shared__ double d[P2T];
    __shared__ int qh[64];
    int t = threadIdx.x;
    int c0 = 2 * t, c1 = 2 * t + 1;
    int v0 = (c0 < nb) ? bsv[c0] : 0;
    int v1 = (c1 < nb) ? bsv[c1] : 0;
    double x0 = (c0 < nb) ? bsc[c0] : 0.0;
    double x1 = (c1 < nb) ? bsc[c1] : 0.0;
    s[t] = v0 + v1; d[t] = x0 + x1;
    if (t < 139) {
        int acc = 0;
        #pragma unroll 8
        for (int sl = 0; sl < NSLICE; ++sl) acc += ghist[sl * 152 + t];
        out_hist[t] = (float)acc;
        if (t < 64) qh[t] = acc;
    }
    __syncthreads();
    for (int off = 1; off < P2T; off <<= 1) {
        int add = (t >= off) ? s[t - off] : 0;
        __syncthreads();
        s[t] += add;
        __syncthreads();
    }
    if (c0 < nb) pos_offset[c0] = s[t] - v0 - v1;
    if (c1 < nb) pos_offset[c1] = s[t] - v1;
    for (int off = P2T / 2; off > 0; off >>= 1) {
        if (t < off) d[t] += d[t + off];
        __syncthreads();
    }
    if (t == 0) {
        int total_v = s[P2T - 1];
        *totalv_p = total_v;
        double vc = (double)(total_v > 1 ? total_v : 1);
        float cur = (float)(d[0] / vc);
        cur = fminf(fmaxf(cur, 1e-4f), 0.9999f);
        float p = fminf(fmaxf(cur, 1e-6f), 0.999999f);
        float lc = logf(p) - log1pf(-p);
        float tgt = (float)(1.0 / 6.0);
        float lt = logf(tgt) - log1pf(-tgt);
        *shiftp = lt - lc;
    }
    if (t < 7) {            // q_weight_hist7[w] = sum over bins with popc==w
        int sacc = 0;
        for (int b = 0; b < 64; ++b) if (__popc(b) == t) sacc += qh[b];
        out_hist[139 + t] = (float)sacc;
    }
    if (t < 6) {            // bit_excitation6[j] = sum qh[b]*bit_j(b)
        int sacc = 0;
        for (int b = 0; b < 64; ++b) sacc += qh[b] * ((b >> t) & 1);
        out_hist[146 + t] = (float)sacc;
    }
}

// ---------------------------------------------------------------------------
// Pass 3 (fused): recompute combined from structural (>0 iff valid) + blp;
// apply shift -> logp/bmask outputs; in-block run lengths via wave scans;
// per-chunk stats for the tiny fix-up pass.
// ---------------------------------------------------------------------------
__global__ __launch_bounds__(TPB, 8) void k_pass3(
    const float* __restrict__ strc, const float* __restrict__ blp,
    const float* __restrict__ shiftp, const int* __restrict__ pos_offset,
    float* __restrict__ out_logp, float* __restrict__ out_bmask,
    float* __restrict__ out_len, int* __restrict__ chunk_cnt,
    int* __restrict__ chunk_last, ull* __restrict__ chunk_first, int n)
{
    __shared__ int swt[4], swm[4], scnt[4];
    __shared__ ull sfirst[4];
    const int tid = threadIdx.x, lane = tid & 63, wave = tid >> 6;
    const long i0 = (long)blockIdx.x * CHUNK + (long)tid * EPT;
    const bool fast = ((long)(blockIdx.x + 1) * CHUNK <= n);
    const float shift = *shiftp;

    float sv8[8], bp8[8];
    if (fast) {
        const float4 s0 = *(const float4*)(strc + i0), s1 = *(const float4*)(strc + i0 + 4);
        const float4 p0 = *(const float4*)(blp + i0),  p1 = *(const float4*)(blp + i0 + 4);
        sv8[0]=s0.x; sv8[1]=s0.y; sv8[2]=s0.z; sv8[3]=s0.w; sv8[4]=s1.x; sv8[5]=s1.y; sv8[6]=s1.z; sv8[7]=s1.w;
        bp8[0]=p0.x; bp8[1]=p0.y; bp8[2]=p0.z; bp8[3]=p0.w; bp8[4]=p1.x; bp8[5]=p1.y; bp8[6]=p1.z; bp8[7]=p1.w;
    } else {
        #pragma unroll
        for (int e = 0; e < 8; ++e) {
            long ii = i0 + e;
            bool r = ii < n;
            sv8[e] = r ? strc[ii] : 0.0f;
            bp8[e] = r ? blp[ii] : 0.0f;
        }
    }

    unsigned mv = 0, mb = 0;
    float lp[8], bmf[8], lenv[8];
    #pragma unroll
    for (int e = 0; e < 8; ++e) {
        float s = sv8[e];
        int v = (s > 0.0f);                       // structural clipped >= 1e-6 iff valid
        float cosine = expf(fminf(bp8[e], 0.0f));
        float comb = 0.5f * (cosine + s);
        float p = fminf(fmaxf(comb, 1e-6f), 0.999999f);
        float z = logf(p) - log1pf(-p) + shift;
        float sgm = 1.0f / (1.0f + expf(-z));
        sgm = fminf(fmaxf(sgm, 1e-6f), 0.999999f);
        float clp = logf(sgm);
        lp[e] = clp;
        int bm = (clp >= -0.69314718f) ? 1 : 0;
        bmf[e] = (float)bm;
        mv |= (unsigned)v << e;
        if (bm & v) mb |= 1u << e;
        lenv[e] = 0.0f;
    }
    if (fast) {
        float4 o;
        o.x=lp[0]; o.y=lp[1]; o.z=lp[2]; o.w=lp[3];     *(float4*)(out_logp + i0) = o;
        o.x=lp[4]; o.y=lp[5]; o.z=lp[6]; o.w=lp[7];     *(float4*)(out_logp + i0 + 4) = o;
        o.x=bmf[0]; o.y=bmf[1]; o.z=bmf[2]; o.w=bmf[3]; *(float4*)(out_bmask + i0) = o;
        o.x=bmf[4]; o.y=bmf[5]; o.z=bmf[6]; o.w=bmf[7]; *(float4*)(out_bmask + i0 + 4) = o;
    } else {
        #pragma unroll
        for (int e = 0; e < 8; ++e)
            if (i0 + e < n) { out_logp[i0 + e] = lp[e]; out_bmask[i0 + e] = bmf[e]; }
    }

    // block-wide exclusive valid-count prefix
    int tvc = __popc(mv);
    int x = tvc;
    #pragma unroll
    for (int off = 1; off < 64; off <<= 1) {
        int y = __shfl_up(x, off, 64);
        if (lane >= off) x += y;
    }
    if (lane == 63) swt[wave] = x;
    __syncthreads();
    int wb = pos_offset[blockIdx.x];
    for (int w2 = 0; w2 < wave; ++w2) wb += swt[w2];
    const int vbase = wb + (x - tvc);

    // last-boundary max-scan + cnt/first reductions
    int last = -1;
    if (mb) {
        int hb = 31 - __clz(mb);
        last = vbase + __popc(mv & ((2u << hb) - 1));
    }
    int m = last;
    #pragma unroll
    for (int off = 1; off < 64; off <<= 1) {
        int y = __shfl_up(m, off, 64);
        if (lane >= off && y > m) m = y;
    }
    int exm = __shfl_up(m, 1, 64);
    if (lane == 0) exm = -1;
    if (lane == 63) swm[wave] = m;
    int cnt = __popc(mb);
    ull fp = ~0ULL;
    if (mb) {
        int lb = __ffs(mb) - 1;
        int fv2 = vbase + __popc(mv & ((2u << lb) - 1));
        fp = ((ull)(unsigned)(i0 + lb) << 32) | (unsigned)fv2;
    }
    #pragma unroll
    for (int off = 32; off > 0; off >>= 1) {
        cnt += __shfl_down(cnt, off, 64);
        ull fo = shfl_down_u64(fp, off);
        if (fo < fp) fp = fo;
    }
    if (lane == 0) { scnt[wave] = cnt; sfirst[wave] = fp; }
    __syncthreads();

    int prev = exm;
    for (int w2 = 0; w2 < wave; ++w2) if (swm[w2] > prev) prev = swm[w2];
    int runv = 0;
    #pragma unroll
    for (int e = 0; e < 8; ++e) {
        runv += (mv >> e) & 1;
        if ((mb >> e) & 1) {
            int pos = vbase + runv;
            lenv[e] = (prev >= 0) ? (float)(pos - prev) : 0.0f;  // first-in-chunk fixed by pass4
            prev = pos;
        }
    }
    if (fast) {
        float4 o;
        o.x=lenv[0]; o.y=lenv[1]; o.z=lenv[2]; o.w=lenv[3]; *(float4*)(out_len + i0) = o;
        o.x=lenv[4]; o.y=lenv[5]; o.z=lenv[6]; o.w=lenv[7]; *(float4*)(out_len + i0 + 4) = o;
    } else {
        #pragma unroll
        for (int e = 0; e < 8; ++e)
            if (i0 + e < n) out_len[i0 + e] = lenv[e];
    }
    if (tid == 0) {
        int c = scnt[0] + scnt[1] + scnt[2] + scnt[3];
        int L = swm[0];
        if (swm[1] > L) L = swm[1];
        if (swm[2] > L) L = swm[2];
        if (swm[3] > L) L = swm[3];
        ull F = sfirst[0];
        if (sfirst[1] < F) F = sfirst[1];
        if (sfirst[2] < F) F = sfirst[2];
        if (sfirst[3] < F) F = sfirst[3];
        chunk_cnt[blockIdx.x] = c;
        chunk_last[blockIdx.x] = L > 0 ? L : 0;
        chunk_first[blockIdx.x] = F;
    }
}

// ---------------------------------------------------------------------------
// Pass 4: tiny scan over per-chunk stats -> first-boundary length fix-up,
// trailing, patch_count. 2 chunks/thread, nb <= 2048.
// ---------------------------------------------------------------------------
__global__ __launch_bounds__(P2T) void k_pass4(
    const int* __restrict__ chunk_cnt, const int* __restrict__ chunk_last,
    const ull* __restrict__ chunk_first, const int* __restrict__ totalv_p,
    int nb, float* __restrict__ out_len,
    float* __restrict__ out_trailing, float* __restrict__ out_patch)
{
    __shared__ int s[P2T];
    __shared__ int cs[P2T];
    int t = threadIdx.x;
    int c0 = 2 * t, c1 = 2 * t + 1;
    int a = 0, b = 0;
    if (c0 < nb) { int z = chunk_last[c0]; a = z > 0 ? z : 0; }
    if (c1 < nb) { int z = chunk_last[c1]; b = z > 0 ? z : 0; }
    int cnt = ((c0 < nb) ? chunk_cnt[c0] : 0) + ((c1 < nb) ? chunk_cnt[c1] : 0);
    s[t] = a > b ? a : b;
    cs[t] = cnt;
    __syncthreads();
    for (int off = 1; off < P2T; off <<= 1) {
        int y = (t >= off) ? s[t - off] : 0;
        __syncthreads();
        if (y > s[t]) s[t] = y;
        __syncthreads();
    }
    int excl = (t > 0) ? s[t - 1] : 0;
    int carry0 = excl;
    int carry1 = excl > a ? excl : a;
    if (c0 < nb) {
        ull F = chunk_first[c0];
        if (F != ~0ULL) {
            int fi = (int)(F >> 32);
            int fv2 = (int)(F & 0xFFFFFFFFu);
            out_len[fi] = (float)(fv2 - carry0);
        }
    }
    if (c1 < nb) {
        ull F = chunk_first[c1];
        if (F != ~0ULL) {
            int fi = (int)(F >> 32);
            int fv2 = (int)(F & 0xFFFFFFFFu);
            out_len[fi] = (float)(fv2 - carry1);
        }
    }
    int gmax = s[P2T - 1];
    __syncthreads();
    for (int off = P2T / 2; off > 0; off >>= 1) {
        if (t < off) cs[t] += cs[t + off];
        __syncthreads();
    }
    if (t == 0) {
        int total_v = *totalv_p;
        int trailing = total_v - gmax;
        int patch = cs[0] + (trailing > 0 ? 1 : 0);
        *out_trailing = (float)trailing;
        *out_patch = (float)patch;
    }
}

// ---------------------------------------------------------------------------
extern "C" void kernel_launch(void* const* d_in, const int* in_sizes, int n_in,
                              void* d_out, int out_size, void* d_ws, size_t ws_size,
                              hipStream_t stream)
{
    const float* blp = (const float*)d_in[0];
    const int* st   = (const int*)d_in[1];
    const int* q    = (const int*)d_in[2];
    const int* fam  = (const int*)d_in[3];
    const int* mic  = (const int*)d_in[4];
    const int* vm   = (const int*)d_in[5];
    const int n = in_sizes[0];
    const int nb = (n + CHUNK - 1) / CHUNK;          // 2048 for n=4M

    float* out = (float*)d_out;
    float* out_logp       = out;
    float* out_bmask      = out + (size_t)n;
    float* out_structural = out + 2 * (size_t)n;
    float* out_hist       = out + 3 * (size_t)n;     // 152 floats
    float* out_len        = out + 3 * (size_t)n + 152;
    float* out_trailing   = out + 4 * (size_t)n + 152;
    float* out_patch      = out + 4 * (size_t)n + 153;

    char* w = (char*)d_ws;
    int*    ghist      = (int*)(w);                  // 64 slices x 152 ints (memset)
    int*    blocksum_v = (int*)(w + 40960);          // nb ints
    int*    pos_offset = (int*)(w + 57344);
    int*    chunk_cnt  = (int*)(w + 73728);
    int*    chunk_last = (int*)(w + 90112);
    float*  shiftp     = (float*)(w + 106496);
    int*    totalv_p   = (int*)(w + 106500);
    double* blocksum_c = (double*)(w + 110592);      // nb doubles
    ull*    chunk_first= (ull*)(w + 131072);         // nb ulls

    hipMemsetAsync(ghist, 0, NSLICE * 152 * 4, stream);

    k_pass1<<<dim3(nb), dim3(TPB), 0, stream>>>(
        blp, st, q, fam, mic, vm, out_structural,
        blocksum_v, blocksum_c, ghist, n);

    k_pass2<<<dim3(1), dim3(P2T), 0, stream>>>(
        blocksum_v, blocksum_c, nb, pos_offset, shiftp, totalv_p,
        ghist, out_hist);

    k_pass3<<<dim3(nb), dim3(TPB), 0, stream>>>(
        out_structural, blp, shiftp, pos_offset, out_logp, out_bmask,
        out_len, chunk_cnt, chunk_last, chunk_first, n);

    k_pass4<<<dim3(1), dim3(P2T), 0, stream>>>(
        chunk_cnt, chunk_last, chunk_first, totalv_p, nb, out_len,
        out_trailing, out_patch);
}